// Round 7
// baseline (252.221 us; speedup 1.0000x reference)
//
#include <hip/hip_runtime.h>

// Causal flash attention, B=4 H=16 S=2048 D=64, fp32 in/out, bf16 MFMA.
// R4: 32x32x16 MFMA, swapped QK^T, softmax fully in registers (cvt_pk +
// permlane32_swap), no P->LDS round-trip. 59.6us fattn, MfmaUtil 23%, occ 32%.
// R5: (a) balanced qb dispatch — per-CU qb quadruples sum to 30 exactly
// (was 24..36, 50% spread -> tail idle); (b) kb-interleaved schedule: QK both
// halves -> sm0 (overlaps QK1 MFMA) -> PV0 -> sm1 (overlaps PV0 MFMA) -> PV1;
// (c) LDS = 32768 exactly (lds_l removed, 1/l broadcast via ds_bpermute) +
// launch_bounds(256,5): 5 blocks/CU fits 160K LDS exactly.

#define S_LEN 2048
#define D_HEAD 64
#define NBH 64      // B*H
#define KTILES 32   // S / 64 (64-key tiles)
#define QROWS 128   // q rows per block
#define NQB 16      // S / QROWS
#define TILE_E 4096 // 64x64 elements per tile image

typedef float f32x4 __attribute__((ext_vector_type(4)));
typedef float f32x16 __attribute__((ext_vector_type(16)));
typedef short s16x8 __attribute__((ext_vector_type(8)));
typedef unsigned int u32;
typedef u32 u32x4 __attribute__((ext_vector_type(4)));

#define SCLOG2E (0.125f * 1.44269504088896340736f)  // 1/sqrt(D) * log2(e)

__device__ __forceinline__ unsigned short f2bf(float x) {  // RNE
    union { float f; unsigned int u; } v; v.f = x;
    unsigned int u = v.u + 0x7FFFu + ((v.u >> 16) & 1u);
    return (unsigned short)(u >> 16);
}

// chunk-rotation swizzle (R1-verified: 0 conflicts on the 16x16 pattern)
__device__ __forceinline__ int swz(int row, int col) {
    return row * 64 + ((((col >> 3) + row) & 7) << 3) + (col & 7);
}

// async global->LDS, 16B per lane; lds dst must be wave-uniform base (lane*16 auto)
__device__ __forceinline__ void g2l(const unsigned short* g, unsigned short* l) {
    __builtin_amdgcn_global_load_lds(
        (const __attribute__((address_space(1))) void*)g,
        (__attribute__((address_space(3))) void*)l, 16, 0, 0);
}

// ---------- pre-pass: fp32 K,V -> bf16 swizzled tile images in workspace ----
__global__ __launch_bounds__(256)
void preconv_kernel(const float* __restrict__ K, const float* __restrict__ V,
                    unsigned short* __restrict__ Kw, unsigned short* __restrict__ Vw)
{
    __shared__ __align__(16) unsigned short vt[TILE_E];
    const int bh = blockIdx.x & (NBH - 1);
    const int j  = blockIdx.x >> 6;
    const float* k = K + (size_t)bh * (S_LEN * D_HEAD) + (size_t)j * 64 * D_HEAD;
    const float* v = V + (size_t)bh * (S_LEN * D_HEAD) + (size_t)j * 64 * D_HEAD;
    const int t = threadIdx.x;
    const size_t tb = (size_t)(bh * KTILES + j) * TILE_E;

    // K tile: row-major [key][d], swizzled, direct global->global (swz stays
    // within each row's 128B line -> stores remain fully coalesced)
#pragma unroll
    for (int i = 0; i < 2; ++i) {
        int chunk = t + 256 * i;
        int row = chunk >> 3, c = chunk & 7;
        const float* p = k + (size_t)row * D_HEAD + c * 8;
        float4 x = *(const float4*)p;
        float4 y = *(const float4*)(p + 4);
        s16x8 f;
        f[0] = (short)f2bf(x.x); f[1] = (short)f2bf(x.y);
        f[2] = (short)f2bf(x.z); f[3] = (short)f2bf(x.w);
        f[4] = (short)f2bf(y.x); f[5] = (short)f2bf(y.y);
        f[6] = (short)f2bf(y.z); f[7] = (short)f2bf(y.w);
        *(s16x8*)&Kw[tb + swz(row, c * 8)] = f;
    }
    // V tile: transposed [d][key], swizzled, via LDS
    {
        int key = t & 63, cc = t >> 6;
#pragma unroll
        for (int ci = 0; ci < 2; ++ci) {
            int c = cc + ci * 4;
            const float* p = v + (size_t)key * D_HEAD + c * 8;
            float4 x = *(const float4*)p;
            float4 y = *(const float4*)(p + 4);
            float vals[8] = {x.x, x.y, x.z, x.w, y.x, y.y, y.z, y.w};
#pragma unroll
            for (int jj = 0; jj < 8; ++jj)
                vt[swz(c * 8 + jj, key)] = f2bf(vals[jj]);
        }
    }
    __syncthreads();
#pragma unroll
    for (int i = 0; i < 2; ++i) {
        int idx = (t + 256 * i) * 8;
        *(s16x8*)&Vw[tb + idx] = *(const s16x8*)&vt[idx];
    }
}

// ---------------------------- main kernel -----------------------------------
template <bool PRE>
__global__ __launch_bounds__(256, 5)
void fattn_kernel(const float* __restrict__ Qg, const float* __restrict__ Kg,
                  const float* __restrict__ Vg, float* __restrict__ Og,
                  const unsigned short* __restrict__ Kw,
                  const unsigned short* __restrict__ Vw)
{
    __shared__ __align__(16) unsigned short ks[2][TILE_E];
    __shared__ __align__(16) unsigned short vs[2][TILE_E];
    // LDS total = 32768 B exactly -> 5 blocks/CU (5*32768 = 163840 = 160 KiB).

    // XCD-affinity decode: bx&7 == XCD (grid 1024). 8 bh per XCD -> KV image
    // working set = 4 MiB = per-XCD L2. Balanced qb order: each CU's 4 blocks
    // get qb from one column of {15,14,13,12|0,1,2,3|11,10,9,8|4,5,6,7} ->
    // per-CU work sums to 30 tile-units uniformly (was 24..36).
    const int bx    = blockIdx.x;
    const int xcd   = bx & 7;
    const int slot  = bx >> 3;                   // 0..127 per XCD
    const int bh    = xcd + ((slot & 7) << 3);
    const int chunk = bx >> 8;                   // 0..3 (dispatch quarter)
    const int sub   = (bx >> 6) & 3;             // 0..3 within quarter
    const int qb    = (chunk == 0) ? 15 - sub
                    : (chunk == 1) ? sub
                    : (chunk == 2) ? 11 - sub
                                   : 4 + sub;
    const size_t base = (size_t)bh * (S_LEN * D_HEAD);
    const float* q = Qg + base;
    const float* k = Kg + base;
    const float* v = Vg + base;
    float*       o = Og + base;

    const int t    = threadIdx.x;
    const int w    = t >> 6;
    const int lane = t & 63;
    const int qc   = lane & 31;     // this lane's q column (32x32 C layout)
    const int hi   = lane >> 5;

    const int qseq = qb * QROWS + w * 32 + qc;   // this lane's q row (absolute)

    // Q B-frags for swapped QK^T: B[k=d][col=q], lane holds q=qc,
    // d = kt*16 + hi*8 + j. scale*log2(e) folded in here.
    s16x8 qa[4];
#pragma unroll
    for (int kt = 0; kt < 4; ++kt) {
        const float* p = q + (size_t)qseq * D_HEAD + kt * 16 + hi * 8;
        float4 x = *(const float4*)p;
        float4 y = *(const float4*)(p + 4);
        s16x8 f;
        f[0] = (short)f2bf(x.x * SCLOG2E); f[1] = (short)f2bf(x.y * SCLOG2E);
        f[2] = (short)f2bf(x.z * SCLOG2E); f[3] = (short)f2bf(x.w * SCLOG2E);
        f[4] = (short)f2bf(y.x * SCLOG2E); f[5] = (short)f2bf(y.y * SCLOG2E);
        f[6] = (short)f2bf(y.z * SCLOG2E); f[7] = (short)f2bf(y.w * SCLOG2E);
        qa[kt] = f;
    }

    f32x16 o0 = {0,0,0,0,0,0,0,0,0,0,0,0,0,0,0,0};
    f32x16 o1 = {0,0,0,0,0,0,0,0,0,0,0,0,0,0,0,0};
    float l = 0.f;

    auto stage = [&](int jt, int buf) {
        if constexpr (PRE) {
            const size_t tb = (size_t)(bh * KTILES + jt) * TILE_E;
#pragma unroll
            for (int i = 0; i < 2; ++i) {
                int c = w * 2 + i;             // 8 chunks of 512 elem (1 KiB)
                g2l(Kw + tb + c * 512 + lane * 8, &ks[buf][c * 512]);
                g2l(Vw + tb + c * 512 + lane * 8, &vs[buf][c * 512]);
            }
        } else {
            const int kb = jt * 64;
#pragma unroll
            for (int i = 0; i < 2; ++i) {
                int chunk2 = t + 256 * i;
                int row = chunk2 >> 3, c = chunk2 & 7;
                const float* p = k + (size_t)(kb + row) * D_HEAD + c * 8;
                float4 x = *(const float4*)p;
                float4 y = *(const float4*)(p + 4);
                s16x8 f;
                f[0] = (short)f2bf(x.x); f[1] = (short)f2bf(x.y);
                f[2] = (short)f2bf(x.z); f[3] = (short)f2bf(x.w);
                f[4] = (short)f2bf(y.x); f[5] = (short)f2bf(y.y);
                f[6] = (short)f2bf(y.z); f[7] = (short)f2bf(y.w);
                *(s16x8*)&ks[buf][swz(row, c * 8)] = f;
            }
            int key = t & 63, cc = t >> 6;
#pragma unroll
            for (int ci = 0; ci < 2; ++ci) {
                int c = cc + ci * 4;
                const float* p = v + (size_t)(kb + key) * D_HEAD + c * 8;
                float4 x = *(const float4*)p;
                float4 y = *(const float4*)(p + 4);
                float vals[8] = {x.x, x.y, x.z, x.w, y.x, y.y, y.z, y.w};
#pragma unroll
                for (int jj = 0; jj < 8; ++jj)
                    vs[buf][swz(c * 8 + jj, key)] = f2bf(vals[jj]);
            }
        }
    };

    const int NT = 2 * qb + 2;       // 64-key tiles this block needs
    stage(0, 0);

    for (int j = 0; j < NT; ++j) {
        const int cur = j & 1;
        __syncthreads();             // drains prefetch DMA (vmcnt) + guards reuse
        if (j + 1 < NT) stage(j + 1, 1 - cur);

        // wave-uniform: skip tiles fully above the diagonal for this wave's q
        if (j * 64 > qb * QROWS + w * 32 + 31) continue;
        const bool domask = (j * 64 + 63 > qb * QROWS + w * 32);

        // ---- softmax half: mask+exp2+rowsum, f32->bf16 pack, permlane -> A-frags.
        // reg r holds key keybase+(r&3)+8*(r>>2)+4*hi; c[i]=pack(sf[2i],sf[2i+1]);
        // swap(c0,c2),(c1,c3): frag m=0 = keys (8*hi..8*hi+7) of [0,15]. ✓
        auto sm = [&](f32x16& sf, int keybase, s16x8& pa0, s16x8& pa1) {
            if (domask) {
#pragma unroll
                for (int r = 0; r < 16; ++r) {
                    int key = keybase + (r & 3) + 8 * (r >> 2) + 4 * hi;
                    sf[r] = (key > qseq) ? -__builtin_inff() : sf[r];
                }
            }
#pragma unroll
            for (int r = 0; r < 16; ++r) sf[r] = __builtin_amdgcn_exp2f(sf[r]);
            {
                float a0 = sf[0] + sf[1],   a1 = sf[2] + sf[3];
                float a2 = sf[4] + sf[5],   a3 = sf[6] + sf[7];
                float a4 = sf[8] + sf[9],   a5 = sf[10] + sf[11];
                float a6 = sf[12] + sf[13], a7 = sf[14] + sf[15];
                float b0 = a0 + a1, b1 = a2 + a3, b2 = a4 + a5, b3 = a6 + a7;
                l += (b0 + b1) + (b2 + b3);
            }
            u32 c[8];
#pragma unroll
            for (int r = 0; r < 8; ++r)
                asm("v_cvt_pk_bf16_f32 %0, %1, %2"
                    : "=v"(c[r]) : "v"(sf[2 * r]), "v"(sf[2 * r + 1]));
            asm("v_permlane32_swap_b32 %0, %1" : "+v"(c[0]), "+v"(c[2]));
            asm("v_permlane32_swap_b32 %0, %1" : "+v"(c[1]), "+v"(c[3]));
            asm("v_permlane32_swap_b32 %0, %1" : "+v"(c[4]), "+v"(c[6]));
            asm("v_permlane32_swap_b32 %0, %1" : "+v"(c[5]), "+v"(c[7]));
            u32x4 t0 = {c[0], c[1], c[2], c[3]};
            u32x4 t1 = {c[4], c[5], c[6], c[7]};
            pa0 = __builtin_bit_cast(s16x8, t0);
            pa1 = __builtin_bit_cast(s16x8, t1);
        };
        // ---- O += P V for one 32-key half (B-frag from V^T image)
        auto pv = [&](int kb, s16x8 pa0, s16x8 pa1) {
#pragma unroll
            for (int m = 0; m < 2; ++m) {
                s16x8 pa = m ? pa1 : pa0;
                int key0 = kb * 32 + m * 16 + hi * 8;
                s16x8 vb0 = *(const s16x8*)&vs[cur][swz(qc, key0)];
                o0 = __builtin_amdgcn_mfma_f32_32x32x16_bf16(pa, vb0, o0, 0, 0, 0);
                s16x8 vb1 = *(const s16x8*)&vs[cur][swz(32 + qc, key0)];
                o1 = __builtin_amdgcn_mfma_f32_32x32x16_bf16(pa, vb1, o1, 0, 0, 0);
            }
        };

        // ---- S^T = K Q: BOTH 32-key halves issued first, so sm0's VALU
        // overlaps QK1's MFMAs and sm1's VALU overlaps PV0's MFMAs.
        f32x16 sf0 = {0,0,0,0,0,0,0,0,0,0,0,0,0,0,0,0};
        f32x16 sf1 = {0,0,0,0,0,0,0,0,0,0,0,0,0,0,0,0};
#pragma unroll
        for (int kt = 0; kt < 4; ++kt) {
            s16x8 ka = *(const s16x8*)&ks[cur][swz(qc, kt * 16 + hi * 8)];
            sf0 = __builtin_amdgcn_mfma_f32_32x32x16_bf16(ka, qa[kt], sf0, 0, 0, 0);
        }
#pragma unroll
        for (int kt = 0; kt < 4; ++kt) {
            s16x8 ka = *(const s16x8*)&ks[cur][swz(32 + qc, kt * 16 + hi * 8)];
            sf1 = __builtin_amdgcn_mfma_f32_32x32x16_bf16(ka, qa[kt], sf1, 0, 0, 0);
        }

        s16x8 p00, p01, p10, p11;
        sm(sf0, j * 64,      p00, p01);
        pv(0, p00, p01);
        sm(sf1, j * 64 + 32, p10, p11);
        pv(1, p10, p11);
    }

    // ---- epilogue: combine partner-half sums; broadcast 1/l via ds_bpermute
    // (register exchange, no LDS buffer). Every lane holds l for row (lane&31)
    // after the shfl; each output reg r needs row rowp's reciprocal.
    l += __shfl_xor(l, 32);
    float linv = 1.f / l;
#pragma unroll
    for (int r = 0; r < 16; ++r) {
        int rowp = (r & 3) + 8 * (r >> 2) + 4 * hi;          // q row in [0,31]
        float inv = __builtin_bit_cast(float,
            __builtin_amdgcn_ds_bpermute(rowp << 2, __builtin_bit_cast(int, linv)));
        int row_g = qb * QROWS + w * 32 + rowp;
        float* po = o + (size_t)row_g * D_HEAD;
        po[qc]      = o0[r] * inv;
        po[32 + qc] = o1[r] * inv;
    }
}

extern "C" void kernel_launch(void* const* d_in, const int* in_sizes, int n_in,
                              void* d_out, int out_size, void* d_ws, size_t ws_size,
                              hipStream_t stream) {
    const float* q = (const float*)d_in[0];
    const float* k = (const float*)d_in[1];
    const float* v = (const float*)d_in[2];
    float* out = (float*)d_out;

    const size_t kv_elems = (size_t)NBH * KTILES * TILE_E;   // 8M elems = 16 MB each
    if (ws_size >= 2 * kv_elems * sizeof(unsigned short)) {
        unsigned short* Kw = (unsigned short*)d_ws;
        unsigned short* Vw = Kw + kv_elems;
        preconv_kernel<<<dim3(NBH * KTILES), dim3(256), 0, stream>>>(k, v, Kw, Vw);
        fattn_kernel<true><<<dim3(NBH * NQB), dim3(256), 0, stream>>>(q, k, v, out, Kw, Vw);
    } else {
        fattn_kernel<false><<<dim3(NBH * NQB), dim3(256), 0, stream>>>(q, k, v, out, nullptr, nullptr);
    }
}

// Round 8
// 188.491 us; speedup vs baseline: 1.3381x; 1.3381x over previous
//
#include <hip/hip_runtime.h>

// Causal flash attention, B=4 H=16 S=2048 D=64, fp32 in/out, bf16 MFMA.
// R4: 32x32x16 MFMA, swapped QK^T, softmax fully in registers (cvt_pk +
// permlane32_swap), no P->LDS round-trip. 59.6us fattn, MfmaUtil 23%, occ 32%.
// R5: balanced qb dispatch + kb-interleave + launch_bounds(256,5) -> REGRESSED
// to 119us: bounds(256,5) capped unified VGPR+AGPR at ~102/wave -> VGPR 48,
// scratch spills (FETCH 33.5->75MB, WRITE 32.7->64.5MB = spill traffic).
// R6: revert ONLY the occupancy lever to (256,4) (128 regs/wave, no spill).
// Keep: balanced qb dispatch (per-CU work sums to 30 tile-units uniformly),
// kb-interleaved schedule (sm VALU overlaps MFMA), 32768B LDS, ds_bpermute
// epilogue, XCD-affinity, bf16 tile images + global_load_lds staging.

#define S_LEN 2048
#define D_HEAD 64
#define NBH 64      // B*H
#define KTILES 32   // S / 64 (64-key tiles)
#define QROWS 128   // q rows per block
#define NQB 16      // S / QROWS
#define TILE_E 4096 // 64x64 elements per tile image

typedef float f32x4 __attribute__((ext_vector_type(4)));
typedef float f32x16 __attribute__((ext_vector_type(16)));
typedef short s16x8 __attribute__((ext_vector_type(8)));
typedef unsigned int u32;
typedef u32 u32x4 __attribute__((ext_vector_type(4)));

#define SCLOG2E (0.125f * 1.44269504088896340736f)  // 1/sqrt(D) * log2(e)

__device__ __forceinline__ unsigned short f2bf(float x) {  // RNE
    union { float f; unsigned int u; } v; v.f = x;
    unsigned int u = v.u + 0x7FFFu + ((v.u >> 16) & 1u);
    return (unsigned short)(u >> 16);
}

// chunk-rotation swizzle (R1-verified: 0 conflicts on the 16x16 pattern)
__device__ __forceinline__ int swz(int row, int col) {
    return row * 64 + ((((col >> 3) + row) & 7) << 3) + (col & 7);
}

// async global->LDS, 16B per lane; lds dst must be wave-uniform base (lane*16 auto)
__device__ __forceinline__ void g2l(const unsigned short* g, unsigned short* l) {
    __builtin_amdgcn_global_load_lds(
        (const __attribute__((address_space(1))) void*)g,
        (__attribute__((address_space(3))) void*)l, 16, 0, 0);
}

// ---------- pre-pass: fp32 K,V -> bf16 swizzled tile images in workspace ----
__global__ __launch_bounds__(256)
void preconv_kernel(const float* __restrict__ K, const float* __restrict__ V,
                    unsigned short* __restrict__ Kw, unsigned short* __restrict__ Vw)
{
    __shared__ __align__(16) unsigned short vt[TILE_E];
    const int bh = blockIdx.x & (NBH - 1);
    const int j  = blockIdx.x >> 6;
    const float* k = K + (size_t)bh * (S_LEN * D_HEAD) + (size_t)j * 64 * D_HEAD;
    const float* v = V + (size_t)bh * (S_LEN * D_HEAD) + (size_t)j * 64 * D_HEAD;
    const int t = threadIdx.x;
    const size_t tb = (size_t)(bh * KTILES + j) * TILE_E;

    // K tile: row-major [key][d], swizzled, direct global->global (swz stays
    // within each row's 128B line -> stores remain fully coalesced)
#pragma unroll
    for (int i = 0; i < 2; ++i) {
        int chunk = t + 256 * i;
        int row = chunk >> 3, c = chunk & 7;
        const float* p = k + (size_t)row * D_HEAD + c * 8;
        float4 x = *(const float4*)p;
        float4 y = *(const float4*)(p + 4);
        s16x8 f;
        f[0] = (short)f2bf(x.x); f[1] = (short)f2bf(x.y);
        f[2] = (short)f2bf(x.z); f[3] = (short)f2bf(x.w);
        f[4] = (short)f2bf(y.x); f[5] = (short)f2bf(y.y);
        f[6] = (short)f2bf(y.z); f[7] = (short)f2bf(y.w);
        *(s16x8*)&Kw[tb + swz(row, c * 8)] = f;
    }
    // V tile: transposed [d][key], swizzled, via LDS
    {
        int key = t & 63, cc = t >> 6;
#pragma unroll
        for (int ci = 0; ci < 2; ++ci) {
            int c = cc + ci * 4;
            const float* p = v + (size_t)key * D_HEAD + c * 8;
            float4 x = *(const float4*)p;
            float4 y = *(const float4*)(p + 4);
            float vals[8] = {x.x, x.y, x.z, x.w, y.x, y.y, y.z, y.w};
#pragma unroll
            for (int jj = 0; jj < 8; ++jj)
                vt[swz(c * 8 + jj, key)] = f2bf(vals[jj]);
        }
    }
    __syncthreads();
#pragma unroll
    for (int i = 0; i < 2; ++i) {
        int idx = (t + 256 * i) * 8;
        *(s16x8*)&Vw[tb + idx] = *(const s16x8*)&vt[idx];
    }
}

// ---------------------------- main kernel -----------------------------------
template <bool PRE>
__global__ __launch_bounds__(256, 4)
void fattn_kernel(const float* __restrict__ Qg, const float* __restrict__ Kg,
                  const float* __restrict__ Vg, float* __restrict__ Og,
                  const unsigned short* __restrict__ Kw,
                  const unsigned short* __restrict__ Vw)
{
    __shared__ __align__(16) unsigned short ks[2][TILE_E];
    __shared__ __align__(16) unsigned short vs[2][TILE_E];
    // LDS = 32768 B; blocks/CU limited by VGPR (4) not LDS.

    // XCD-affinity decode: bx&7 == XCD (grid 1024). 8 bh per XCD -> KV image
    // working set = 4 MiB = per-XCD L2. Balanced qb order: each CU's 4 blocks
    // get qb from one column of {15,14,13,12|0,1,2,3|11,10,9,8|4,5,6,7} ->
    // per-CU work sums to 30 tile-units uniformly (was 24..36).
    const int bx    = blockIdx.x;
    const int xcd   = bx & 7;
    const int slot  = bx >> 3;                   // 0..127 per XCD
    const int bh    = xcd + ((slot & 7) << 3);
    const int chunk = bx >> 8;                   // 0..3 (dispatch quarter)
    const int sub   = (bx >> 6) & 3;             // 0..3 within quarter
    const int qb    = (chunk == 0) ? 15 - sub
                    : (chunk == 1) ? sub
                    : (chunk == 2) ? 11 - sub
                                   : 4 + sub;
    const size_t base = (size_t)bh * (S_LEN * D_HEAD);
    const float* q = Qg + base;
    const float* k = Kg + base;
    const float* v = Vg + base;
    float*       o = Og + base;

    const int t    = threadIdx.x;
    const int w    = t >> 6;
    const int lane = t & 63;
    const int qc   = lane & 31;     // this lane's q column (32x32 C layout)
    const int hi   = lane >> 5;

    const int qseq = qb * QROWS + w * 32 + qc;   // this lane's q row (absolute)

    // Q B-frags for swapped QK^T: B[k=d][col=q], lane holds q=qc,
    // d = kt*16 + hi*8 + j. scale*log2(e) folded in here.
    s16x8 qa[4];
#pragma unroll
    for (int kt = 0; kt < 4; ++kt) {
        const float* p = q + (size_t)qseq * D_HEAD + kt * 16 + hi * 8;
        float4 x = *(const float4*)p;
        float4 y = *(const float4*)(p + 4);
        s16x8 f;
        f[0] = (short)f2bf(x.x * SCLOG2E); f[1] = (short)f2bf(x.y * SCLOG2E);
        f[2] = (short)f2bf(x.z * SCLOG2E); f[3] = (short)f2bf(x.w * SCLOG2E);
        f[4] = (short)f2bf(y.x * SCLOG2E); f[5] = (short)f2bf(y.y * SCLOG2E);
        f[6] = (short)f2bf(y.z * SCLOG2E); f[7] = (short)f2bf(y.w * SCLOG2E);
        qa[kt] = f;
    }

    f32x16 o0 = {0,0,0,0,0,0,0,0,0,0,0,0,0,0,0,0};
    f32x16 o1 = {0,0,0,0,0,0,0,0,0,0,0,0,0,0,0,0};
    float l = 0.f;

    auto stage = [&](int jt, int buf) {
        if constexpr (PRE) {
            const size_t tb = (size_t)(bh * KTILES + jt) * TILE_E;
#pragma unroll
            for (int i = 0; i < 2; ++i) {
                int c = w * 2 + i;             // 8 chunks of 512 elem (1 KiB)
                g2l(Kw + tb + c * 512 + lane * 8, &ks[buf][c * 512]);
                g2l(Vw + tb + c * 512 + lane * 8, &vs[buf][c * 512]);
            }
        } else {
            const int kb = jt * 64;
#pragma unroll
            for (int i = 0; i < 2; ++i) {
                int chunk2 = t + 256 * i;
                int row = chunk2 >> 3, c = chunk2 & 7;
                const float* p = k + (size_t)(kb + row) * D_HEAD + c * 8;
                float4 x = *(const float4*)p;
                float4 y = *(const float4*)(p + 4);
                s16x8 f;
                f[0] = (short)f2bf(x.x); f[1] = (short)f2bf(x.y);
                f[2] = (short)f2bf(x.z); f[3] = (short)f2bf(x.w);
                f[4] = (short)f2bf(y.x); f[5] = (short)f2bf(y.y);
                f[6] = (short)f2bf(y.z); f[7] = (short)f2bf(y.w);
                *(s16x8*)&ks[buf][swz(row, c * 8)] = f;
            }
            int key = t & 63, cc = t >> 6;
#pragma unroll
            for (int ci = 0; ci < 2; ++ci) {
                int c = cc + ci * 4;
                const float* p = v + (size_t)(kb + key) * D_HEAD + c * 8;
                float4 x = *(const float4*)p;
                float4 y = *(const float4*)(p + 4);
                float vals[8] = {x.x, x.y, x.z, x.w, y.x, y.y, y.z, y.w};
#pragma unroll
                for (int jj = 0; jj < 8; ++jj)
                    vs[buf][swz(c * 8 + jj, key)] = f2bf(vals[jj]);
            }
        }
    };

    const int NT = 2 * qb + 2;       // 64-key tiles this block needs
    stage(0, 0);

    for (int j = 0; j < NT; ++j) {
        const int cur = j & 1;
        __syncthreads();             // drains prefetch DMA (vmcnt) + guards reuse
        if (j + 1 < NT) stage(j + 1, 1 - cur);

        // wave-uniform: skip tiles fully above the diagonal for this wave's q
        if (j * 64 > qb * QROWS + w * 32 + 31) continue;
        const bool domask = (j * 64 + 63 > qb * QROWS + w * 32);

        // ---- softmax half: mask+exp2+rowsum, f32->bf16 pack, permlane -> A-frags.
        // reg r holds key keybase+(r&3)+8*(r>>2)+4*hi; c[i]=pack(sf[2i],sf[2i+1]);
        // swap(c0,c2),(c1,c3): frag m=0 = keys (8*hi..8*hi+7) of [0,15]. ✓
        auto sm = [&](f32x16& sf, int keybase, s16x8& pa0, s16x8& pa1) {
            if (domask) {
#pragma unroll
                for (int r = 0; r < 16; ++r) {
                    int key = keybase + (r & 3) + 8 * (r >> 2) + 4 * hi;
                    sf[r] = (key > qseq) ? -__builtin_inff() : sf[r];
                }
            }
#pragma unroll
            for (int r = 0; r < 16; ++r) sf[r] = __builtin_amdgcn_exp2f(sf[r]);
            {
                float a0 = sf[0] + sf[1],   a1 = sf[2] + sf[3];
                float a2 = sf[4] + sf[5],   a3 = sf[6] + sf[7];
                float a4 = sf[8] + sf[9],   a5 = sf[10] + sf[11];
                float a6 = sf[12] + sf[13], a7 = sf[14] + sf[15];
                float b0 = a0 + a1, b1 = a2 + a3, b2 = a4 + a5, b3 = a6 + a7;
                l += (b0 + b1) + (b2 + b3);
            }
            u32 c[8];
#pragma unroll
            for (int r = 0; r < 8; ++r)
                asm("v_cvt_pk_bf16_f32 %0, %1, %2"
                    : "=v"(c[r]) : "v"(sf[2 * r]), "v"(sf[2 * r + 1]));
            asm("v_permlane32_swap_b32 %0, %1" : "+v"(c[0]), "+v"(c[2]));
            asm("v_permlane32_swap_b32 %0, %1" : "+v"(c[1]), "+v"(c[3]));
            asm("v_permlane32_swap_b32 %0, %1" : "+v"(c[4]), "+v"(c[6]));
            asm("v_permlane32_swap_b32 %0, %1" : "+v"(c[5]), "+v"(c[7]));
            u32x4 t0 = {c[0], c[1], c[2], c[3]};
            u32x4 t1 = {c[4], c[5], c[6], c[7]};
            pa0 = __builtin_bit_cast(s16x8, t0);
            pa1 = __builtin_bit_cast(s16x8, t1);
        };
        // ---- O += P V for one 32-key half (B-frag from V^T image)
        auto pv = [&](int kb, s16x8 pa0, s16x8 pa1) {
#pragma unroll
            for (int m = 0; m < 2; ++m) {
                s16x8 pa = m ? pa1 : pa0;
                int key0 = kb * 32 + m * 16 + hi * 8;
                s16x8 vb0 = *(const s16x8*)&vs[cur][swz(qc, key0)];
                o0 = __builtin_amdgcn_mfma_f32_32x32x16_bf16(pa, vb0, o0, 0, 0, 0);
                s16x8 vb1 = *(const s16x8*)&vs[cur][swz(32 + qc, key0)];
                o1 = __builtin_amdgcn_mfma_f32_32x32x16_bf16(pa, vb1, o1, 0, 0, 0);
            }
        };

        // ---- S^T = K Q: BOTH 32-key halves issued first, so sm0's VALU
        // overlaps QK1's MFMAs and sm1's VALU overlaps PV0's MFMAs.
        f32x16 sf0 = {0,0,0,0,0,0,0,0,0,0,0,0,0,0,0,0};
        f32x16 sf1 = {0,0,0,0,0,0,0,0,0,0,0,0,0,0,0,0};
#pragma unroll
        for (int kt = 0; kt < 4; ++kt) {
            s16x8 ka = *(const s16x8*)&ks[cur][swz(qc, kt * 16 + hi * 8)];
            sf0 = __builtin_amdgcn_mfma_f32_32x32x16_bf16(ka, qa[kt], sf0, 0, 0, 0);
        }
#pragma unroll
        for (int kt = 0; kt < 4; ++kt) {
            s16x8 ka = *(const s16x8*)&ks[cur][swz(32 + qc, kt * 16 + hi * 8)];
            sf1 = __builtin_amdgcn_mfma_f32_32x32x16_bf16(ka, qa[kt], sf1, 0, 0, 0);
        }

        s16x8 p00, p01, p10, p11;
        sm(sf0, j * 64,      p00, p01);
        pv(0, p00, p01);
        sm(sf1, j * 64 + 32, p10, p11);
        pv(1, p10, p11);
    }

    // ---- epilogue: combine partner-half sums; broadcast 1/l via ds_bpermute
    // (register exchange, no LDS buffer). Every lane holds l for row (lane&31)
    // after the shfl; each output reg r needs row rowp's reciprocal.
    l += __shfl_xor(l, 32);
    float linv = 1.f / l;
#pragma unroll
    for (int r = 0; r < 16; ++r) {
        int rowp = (r & 3) + 8 * (r >> 2) + 4 * hi;          // q row in [0,31]
        float inv = __builtin_bit_cast(float,
            __builtin_amdgcn_ds_bpermute(rowp << 2, __builtin_bit_cast(int, linv)));
        int row_g = qb * QROWS + w * 32 + rowp;
        float* po = o + (size_t)row_g * D_HEAD;
        po[qc]      = o0[r] * inv;
        po[32 + qc] = o1[r] * inv;
    }
}

extern "C" void kernel_launch(void* const* d_in, const int* in_sizes, int n_in,
                              void* d_out, int out_size, void* d_ws, size_t ws_size,
                              hipStream_t stream) {
    const float* q = (const float*)d_in[0];
    const float* k = (const float*)d_in[1];
    const float* v = (const float*)d_in[2];
    float* out = (float*)d_out;

    const size_t kv_elems = (size_t)NBH * KTILES * TILE_E;   // 8M elems = 16 MB each
    if (ws_size >= 2 * kv_elems * sizeof(unsigned short)) {
        unsigned short* Kw = (unsigned short*)d_ws;
        unsigned short* Vw = Kw + kv_elems;
        preconv_kernel<<<dim3(NBH * KTILES), dim3(256), 0, stream>>>(k, v, Kw, Vw);
        fattn_kernel<true><<<dim3(NBH * NQB), dim3(256), 0, stream>>>(q, k, v, out, Kw, Vw);
    } else {
        fattn_kernel<false><<<dim3(NBH * NQB), dim3(256), 0, stream>>>(q, k, v, out, nullptr, nullptr);
    }
}